// Round 1
// baseline (1153.897 us; speedup 1.0000x reference)
//
#include <hip/hip_runtime.h>
#include <hip/hip_bf16.h>

#define NROWS 4096
#define NV    204
#define NH    128
#define NG    256

typedef __bf16 bf16x8 __attribute__((ext_vector_type(8)));
typedef __bf16 bf16x4 __attribute__((ext_vector_type(4)));
typedef float  f32x4  __attribute__((ext_vector_type(4)));

__device__ __forceinline__ float elu_f(float x)  { return x > 0.f ? x : __expf(x) - 1.f; }
__device__ __forceinline__ float sigm_f(float x) { return 1.f / (1.f + __expf(-x)); }

// ---------------- prep: fc2t[v][n][k] = (bf16) fc2_w[v][k][n] ----------------
__global__ __launch_bounds__(256) void k_prep_fc2(const float* __restrict__ src,
                                                  __bf16* __restrict__ dst)
{
    __shared__ float tile[64 * 129];
    const int v = blockIdx.x;
    const float* s = src + (size_t)v * (NH * NH);
    __bf16*      d = dst + (size_t)v * (NH * NH);
    for (int h = 0; h < 2; ++h) {
        __syncthreads();
        for (int i = threadIdx.x; i < 64 * 128; i += 256) {
            const int k = i >> 7, n = i & 127;
            tile[k * 129 + n] = s[(h * 64 + k) * 128 + n];
        }
        __syncthreads();
        for (int i = threadIdx.x; i < 64 * 128; i += 256) {
            const int n = i >> 6, kk = i & 63;
            d[n * 128 + h * 64 + kk] = (__bf16)tile[kk * 129 + n];
        }
    }
}

// ---------------- prep: glu16[i] = (bf16) glu_w[i] ----------------
__global__ __launch_bounds__(256) void k_cvt_glu(const float4* __restrict__ src,
                                                 __bf16* __restrict__ dst, int n4)
{
    const int i = blockIdx.x * 256 + threadIdx.x;
    if (i < n4) {
        const float4 f = src[i];
        bf16x4 o;
        o[0] = (__bf16)f.x; o[1] = (__bf16)f.y; o[2] = (__bf16)f.z; o[3] = (__bf16)f.w;
        *reinterpret_cast<bf16x4*>(dst + (size_t)i * 4) = o;
    }
}

// ---------------- weight path: wts = softmax(LN(x + GLU(MLP(x)))) ----------------
__global__ __launch_bounds__(256) void k_wts(const float* __restrict__ xs,
    const float* __restrict__ wfc1_w, const float* __restrict__ wfc1_b,
    const float* __restrict__ wfc2_w, const float* __restrict__ wfc2_b,
    const float* __restrict__ wglu_w, const float* __restrict__ wglu_b,
    const float* __restrict__ wln_g,  const float* __restrict__ wln_b,
    float* __restrict__ wts)
{
    __shared__ float sx[16][NV];
    __shared__ float sa[16][NH];
    __shared__ float sg[16][2 * NV];
    const int t  = threadIdx.x;
    const int tr = t >> 4;
    const int tc = t & 15;
    const int r0 = blockIdx.x * 16;

    for (int i = t; i < 16 * NV; i += 256) {
        const int r = i / NV, c = i - r * NV;
        sx[r][c] = xs[(size_t)(r0 + r) * NV + c];
    }
    __syncthreads();

    // a1 = elu(x @ wfc1_w + b)
    float a1v[8];
    #pragma unroll
    for (int j = 0; j < 8; ++j) {
        const int h = tc + 16 * j;
        float acc = wfc1_b[h];
        #pragma unroll 4
        for (int v = 0; v < NV; ++v) acc = fmaf(sx[tr][v], wfc1_w[v * NH + h], acc);
        a1v[j] = elu_f(acc);
    }
    #pragma unroll
    for (int j = 0; j < 8; ++j) sa[tr][tc + 16 * j] = a1v[j];
    __syncthreads();

    // a2 = a1 @ wfc2_w + b
    float a2v[8];
    #pragma unroll
    for (int j = 0; j < 8; ++j) {
        const int h2 = tc + 16 * j;
        float acc = wfc2_b[h2];
        #pragma unroll 4
        for (int h = 0; h < NH; ++h) acc = fmaf(sa[tr][h], wfc2_w[h * NH + h2], acc);
        a2v[j] = acc;
    }
    __syncthreads();
    #pragma unroll
    for (int j = 0; j < 8; ++j) sa[tr][tc + 16 * j] = a2v[j];
    __syncthreads();

    // g = a2 @ wglu_w + b  (408 cols)
    for (int gi = tc; gi < 2 * NV; gi += 16) {
        float acc = wglu_b[gi];
        #pragma unroll 4
        for (int h = 0; h < NH; ++h) acc = fmaf(sa[tr][h], wglu_w[h * (2 * NV) + gi], acc);
        sg[tr][gi] = acc;
    }
    __syncthreads();

    // hg = g[:V]*sigmoid(g[V:]); t = x + hg; LN over 204; softmax
    float tv[13];
    float s1 = 0.f, s2 = 0.f;
    #pragma unroll
    for (int ii = 0; ii < 13; ++ii) {
        const int c = tc + 16 * ii;
        float val = 0.f;
        if (c < NV) {
            const float hg = sg[tr][c] * sigm_f(sg[tr][c + NV]);
            val = sx[tr][c] + hg;
            s1 += val; s2 = fmaf(val, val, s2);
        }
        tv[ii] = val;
    }
    #pragma unroll
    for (int m = 1; m <= 8; m <<= 1) { s1 += __shfl_xor(s1, m); s2 += __shfl_xor(s2, m); }
    const float mu  = s1 * (1.f / 204.f);
    const float var = s2 * (1.f / 204.f) - mu * mu;
    const float rs  = rsqrtf(fmaxf(var, 0.f) + 1e-5f);

    float mx = -1e30f;
    #pragma unroll
    for (int ii = 0; ii < 13; ++ii) {
        const int c = tc + 16 * ii;
        if (c < NV) {
            const float y = fmaf((tv[ii] - mu) * rs, wln_g[c], wln_b[c]);
            tv[ii] = y;
            mx = fmaxf(mx, y);
        }
    }
    #pragma unroll
    for (int m = 1; m <= 8; m <<= 1) mx = fmaxf(mx, __shfl_xor(mx, m));
    float se = 0.f;
    #pragma unroll
    for (int ii = 0; ii < 13; ++ii) {
        const int c = tc + 16 * ii;
        if (c < NV) {
            const float e = __expf(tv[ii] - mx);
            tv[ii] = e;
            se += e;
        }
    }
    #pragma unroll
    for (int m = 1; m <= 8; m <<= 1) se += __shfl_xor(se, m);
    const float inv = 1.f / se;
    #pragma unroll
    for (int ii = 0; ii < 13; ++ii) {
        const int c = tc + 16 * ii;
        if (c < NV) wts[(size_t)(r0 + tr) * NV + c] = tv[ii] * inv;
    }
}

// ---------------- main fused kernel ----------------
// grid = 256 M-tiles x 8 v-groups; block = 256 (4 waves); each wave: one 16-row
// M-tile, loops its v subset; per v: A1(elu) -> MFMA GEMM1 -> LDS swizzle ->
// MFMA GEMM2 -> GLU -> skip -> LN -> acc_out += wts * var_out; epilogue reduce.
__global__ __launch_bounds__(256) void k_main(
    const float*  __restrict__ xs,
    const float*  __restrict__ fc1_w,
    const float*  __restrict__ fc1_b,
    const float*  __restrict__ fc2_b,
    const float*  __restrict__ glu_b,
    const float*  __restrict__ skip_w,
    const float*  __restrict__ skip_b,
    const float*  __restrict__ ln_g,
    const float*  __restrict__ ln_b,
    const __bf16* __restrict__ fc2t,   // [v][n][k] bf16
    const __bf16* __restrict__ glu16,  // [v][g][k] bf16
    const float*  __restrict__ wts,
    float*        __restrict__ out)
{
    __shared__ union LdsT {
        __bf16 h2[4][2][16 * NH];   // [wave][buf][row*128 + swizzled k2]
        float  red[4][16 * NH];
    } lds;

    const int tid = threadIdx.x;
    const int w   = tid >> 6;
    const int l   = tid & 63;
    const int l15 = l & 15;
    const int lg  = l >> 4;

    const int vg = blockIdx.x & 7;          // v-group == XCD (round-robin dispatch)
    const int m0 = (blockIdx.x >> 3) * 16;  // token-row base

    float lngv[8], lnbv[8];
    #pragma unroll
    for (int j = 0; j < 8; ++j) {
        lngv[j] = ln_g[j * 16 + l15];
        lnbv[j] = ln_b[j * 16 + l15];
    }

    const f32x4 zero4 = {0.f, 0.f, 0.f, 0.f};
    f32x4 acc_out[8];
    #pragma unroll
    for (int j = 0; j < 8; ++j) acc_out[j] = zero4;

    int par = 0;
    for (int i = w; vg + 8 * i < NV; i += 4) {
        const int v = vg + 8 * i;

        const float xv = xs[(size_t)(m0 + l15) * NV + v];
        const float wv = wts[(size_t)(m0 + l15) * NV + v];

        // ---- A1 fragments: row = l15, k = kb*32 + lg*8 + b
        bf16x8 a1[4];
        #pragma unroll
        for (int kb = 0; kb < 4; ++kb) {
            const int k0 = kb * 32 + lg * 8;
            const float4 w0 = *(const float4*)(fc1_w + v * NH + k0);
            const float4 w1 = *(const float4*)(fc1_w + v * NH + k0 + 4);
            const float4 b0 = *(const float4*)(fc1_b + v * NH + k0);
            const float4 b1 = *(const float4*)(fc1_b + v * NH + k0 + 4);
            bf16x8 af;
            af[0] = (__bf16)elu_f(fmaf(xv, w0.x, b0.x));
            af[1] = (__bf16)elu_f(fmaf(xv, w0.y, b0.y));
            af[2] = (__bf16)elu_f(fmaf(xv, w0.z, b0.z));
            af[3] = (__bf16)elu_f(fmaf(xv, w0.w, b0.w));
            af[4] = (__bf16)elu_f(fmaf(xv, w1.x, b1.x));
            af[5] = (__bf16)elu_f(fmaf(xv, w1.y, b1.y));
            af[6] = (__bf16)elu_f(fmaf(xv, w1.z, b1.z));
            af[7] = (__bf16)elu_f(fmaf(xv, w1.w, b1.w));
            a1[kb] = af;
        }

        // ---- GEMM1: h2 = h1 @ fc2_w[v] + fc2_b -> LDS (bf16, XOR-swizzled)
        __bf16* h2b = &lds.h2[w][par][0];
        #pragma unroll
        for (int j = 0; j < 8; ++j) {
            f32x4 acc = zero4;
            const __bf16* bp = fc2t + ((size_t)v * NH + j * 16 + l15) * NH + lg * 8;
            #pragma unroll
            for (int kb = 0; kb < 4; ++kb) {
                const bf16x8 bf = *(const bf16x8*)(bp + kb * 32);
                acc = __builtin_amdgcn_mfma_f32_16x16x32_bf16(a1[kb], bf, acc, 0, 0, 0);
            }
            const float bias = fc2_b[v * NH + j * 16 + l15];
            const int colb = (j * 16 + l15) * 2;
            #pragma unroll
            for (int r = 0; r < 4; ++r) {
                const int row = lg * 4 + r;   // D row = (lane>>4)*4 + reg  [m89]
                h2b[row * NH + ((colb ^ ((row & 7) << 4)) >> 1)] = (__bf16)(acc[r] + bias);
            }
        }

        asm volatile("s_waitcnt lgkmcnt(0)" ::: "memory");  // wave-local LDS flush

        // ---- A2 fragments: row = l15, k2 = kb*32 + lg*8 + b (same swizzle)
        bf16x8 a2[4];
        #pragma unroll
        for (int kb = 0; kb < 4; ++kb) {
            const int off = ((kb * 64 + lg * 16) ^ ((l15 & 7) << 4)) >> 1;
            a2[kb] = *(const bf16x8*)(h2b + l15 * NH + off);
        }

        // ---- GEMM2: glu = h2 @ glu_w[v]^T + glu_b
        f32x4 acc2[16];
        #pragma unroll
        for (int j2 = 0; j2 < 16; ++j2) {
            f32x4 acc = zero4;
            const __bf16* bp2 = glu16 + ((size_t)v * NG + j2 * 16 + l15) * NH + lg * 8;
            #pragma unroll
            for (int kb = 0; kb < 4; ++kb) {
                const bf16x8 bf = *(const bf16x8*)(bp2 + kb * 32);
                acc = __builtin_amdgcn_mfma_f32_16x16x32_bf16(a2[kb], bf, acc, 0, 0, 0);
            }
            const float gb = glu_b[v * NG + j2 * 16 + l15];
            acc[0] += gb; acc[1] += gb; acc[2] += gb; acc[3] += gb;
            acc2[j2] = acc;
        }

        // x / wts broadcast to D rows (rows 0..15 live in lanes 0..15)
        float xrow[4], wrow[4];
        #pragma unroll
        for (int r = 0; r < 4; ++r) {
            xrow[r] = __shfl(xv, lg * 4 + r);
            wrow[r] = __shfl(wv, lg * 4 + r);
        }

        // ---- GLU + skip
        float sv[8][4];
        #pragma unroll
        for (int j = 0; j < 8; ++j) {
            const float sw = skip_w[v * NH + j * 16 + l15];
            const float sb = skip_b[v * NH + j * 16 + l15];
            #pragma unroll
            for (int r = 0; r < 4; ++r) {
                const float h3 = acc2[j][r] * sigm_f(acc2[j + 8][r]);
                sv[j][r] = fmaf(xrow[r], sw, sb) + h3;
            }
        }

        // ---- LN over H per row + weighted accumulate
        #pragma unroll
        for (int r = 0; r < 4; ++r) {
            float s1 = 0.f, s2 = 0.f;
            #pragma unroll
            for (int j = 0; j < 8; ++j) { s1 += sv[j][r]; s2 = fmaf(sv[j][r], sv[j][r], s2); }
            #pragma unroll
            for (int m = 1; m <= 8; m <<= 1) { s1 += __shfl_xor(s1, m); s2 += __shfl_xor(s2, m); }
            const float mu  = s1 * (1.f / 128.f);
            const float var = s2 * (1.f / 128.f) - mu * mu;
            const float rsv = rsqrtf(fmaxf(var, 0.f) + 1e-5f);
            const float wt  = wrow[r];
            #pragma unroll
            for (int j = 0; j < 8; ++j) {
                const float y = fmaf((sv[j][r] - mu) * rsv, lngv[j], lnbv[j]);
                acc_out[j][r] = fmaf(wt, y, acc_out[j][r]);
            }
        }

        par ^= 1;
    }

    // ---- block-level reduction of 4 wave partials, then atomic into out
    __syncthreads();
    #pragma unroll
    for (int j = 0; j < 8; ++j) {
        #pragma unroll
        for (int r = 0; r < 4; ++r)
            lds.red[w][(lg * 4 + r) * NH + j * 16 + l15] = acc_out[j][r];
    }
    __syncthreads();

    #pragma unroll
    for (int q = 0; q < 8; ++q) {
        const int e = q * 256 + tid;
        const float sum = lds.red[0][e] + lds.red[1][e] + lds.red[2][e] + lds.red[3][e];
        const int row = e >> 7, col = e & 127;
        atomicAdd(&out[(size_t)(m0 + row) * NH + col], sum);
    }
}

extern "C" void kernel_launch(void* const* d_in, const int* in_sizes, int n_in,
                              void* d_out, int out_size, void* d_ws, size_t ws_size,
                              hipStream_t stream) {
    (void)in_sizes; (void)n_in; (void)out_size; (void)ws_size;

    const float* xs     = (const float*)d_in[0];
    const float* fc1_w  = (const float*)d_in[1];
    const float* fc1_b  = (const float*)d_in[2];
    const float* fc2_w  = (const float*)d_in[3];
    const float* fc2_b  = (const float*)d_in[4];
    const float* glu_w  = (const float*)d_in[5];
    const float* glu_b  = (const float*)d_in[6];
    const float* skip_w = (const float*)d_in[7];
    const float* skip_b = (const float*)d_in[8];
    const float* ln_g   = (const float*)d_in[9];
    const float* ln_b   = (const float*)d_in[10];
    const float* wfc1_w = (const float*)d_in[11];
    const float* wfc1_b = (const float*)d_in[12];
    const float* wfc2_w = (const float*)d_in[13];
    const float* wfc2_b = (const float*)d_in[14];
    const float* wglu_w = (const float*)d_in[15];
    const float* wglu_b = (const float*)d_in[16];
    const float* wln_g  = (const float*)d_in[17];
    const float* wln_b  = (const float*)d_in[18];

    float* out = (float*)d_out;
    float* wts = out + (size_t)NROWS * NH;

    __bf16* fc2t  = (__bf16*)d_ws;
    __bf16* glu16 = fc2t + (size_t)NV * NH * NH;

    hipMemsetAsync(d_out, 0, (size_t)NROWS * NH * sizeof(float), stream);

    k_prep_fc2<<<NV, 256, 0, stream>>>(fc2_w, fc2t);

    const int n4 = NV * NG * NH / 4;
    k_cvt_glu<<<(n4 + 255) / 256, 256, 0, stream>>>((const float4*)glu_w, glu16, n4);

    k_wts<<<NROWS / 16, 256, 0, stream>>>(xs, wfc1_w, wfc1_b, wfc2_w, wfc2_b,
                                          wglu_w, wglu_b, wln_g, wln_b, wts);

    k_main<<<(NROWS / 16) * 8, 256, 0, stream>>>(xs, fc1_w, fc1_b, fc2_b, glu_b,
                                                 skip_w, skip_b, ln_g, ln_b,
                                                 fc2t, glu16, wts, out);
}

// Round 2
// 567.211 us; speedup vs baseline: 2.0343x; 2.0343x over previous
//
#include <hip/hip_runtime.h>
#include <hip/hip_bf16.h>

#define NROWS 4096
#define NV    204
#define NH    128
#define NG    256

typedef __bf16 bf16x8 __attribute__((ext_vector_type(8)));
typedef __bf16 bf16x4 __attribute__((ext_vector_type(4)));
typedef float  f32x4  __attribute__((ext_vector_type(4)));

__device__ __forceinline__ float elu_f(float x)  { return x > 0.f ? x : __expf(x) - 1.f; }
__device__ __forceinline__ float sigm_f(float x) { return 1.f / (1.f + __expf(-x)); }

__device__ __forceinline__ void stage16(const void* g, void* l) {
    __builtin_amdgcn_global_load_lds((const __attribute__((address_space(1))) void*)g,
                                     (__attribute__((address_space(3))) void*)l, 16, 0, 0);
}

// ---------------- prep: fc2t[v][n][k] = (bf16) fc2_w[v][k][n] ----------------
__global__ __launch_bounds__(256) void k_prep_fc2(const float* __restrict__ src,
                                                  __bf16* __restrict__ dst)
{
    __shared__ float tile[64 * 129];
    const int v = blockIdx.x;
    const float* s = src + (size_t)v * (NH * NH);
    __bf16*      d = dst + (size_t)v * (NH * NH);
    for (int h = 0; h < 2; ++h) {
        __syncthreads();
        for (int i = threadIdx.x; i < 64 * 32; i += 256) {
            const int k = i >> 5, n4 = (i & 31) * 4;
            const float4 f = *(const float4*)(s + (h * 64 + k) * 128 + n4);
            tile[k * 129 + n4 + 0] = f.x;
            tile[k * 129 + n4 + 1] = f.y;
            tile[k * 129 + n4 + 2] = f.z;
            tile[k * 129 + n4 + 3] = f.w;
        }
        __syncthreads();
        for (int i = threadIdx.x; i < 128 * 8; i += 256) {
            const int n = i >> 3, kc = (i & 7) * 8;
            bf16x8 o;
            #pragma unroll
            for (int q = 0; q < 8; ++q) o[q] = (__bf16)tile[(kc + q) * 129 + n];
            *(bf16x8*)(d + n * 128 + h * 64 + kc) = o;
        }
    }
}

// ------- prep: glu16 pre-swizzled: chunk ch of row g stored at ch^(g&7) -------
__global__ __launch_bounds__(256) void k_cvt_glu(const float* __restrict__ src,
                                                 __bf16* __restrict__ dst)
{
    const int idx = blockIdx.x * 256 + threadIdx.x;   // one 16B dst chunk
    if (idx >= NV * NG * (NH / 8)) return;
    const int ch = idx & 15;
    const int g  = (idx >> 4) & 255;
    const int v  = idx >> 12;
    const float* sp = src + (((size_t)v * NG + g) * NH + ch * 8);
    bf16x8 o;
    #pragma unroll
    for (int q = 0; q < 8; ++q) o[q] = (__bf16)sp[q];
    const int dch = ch ^ (g & 7);
    *(bf16x8*)(dst + (((size_t)v * NG + g) * NH) + dch * 8) = o;
}

// ---------------- weight path: wts = softmax(LN(x + GLU(MLP(x)))) ----------------
__global__ __launch_bounds__(256) void k_wts(const float* __restrict__ xs,
    const float* __restrict__ wfc1_w, const float* __restrict__ wfc1_b,
    const float* __restrict__ wfc2_w, const float* __restrict__ wfc2_b,
    const float* __restrict__ wglu_w, const float* __restrict__ wglu_b,
    const float* __restrict__ wln_g,  const float* __restrict__ wln_b,
    float* __restrict__ wts)
{
    __shared__ float sx[16][NV];
    __shared__ float sa[16][NH];
    __shared__ float sg[16][2 * NV];
    const int t  = threadIdx.x;
    const int tr = t >> 4;
    const int tc = t & 15;
    const int r0 = blockIdx.x * 16;

    for (int i = t; i < 16 * NV; i += 256) {
        const int r = i / NV, c = i - r * NV;
        sx[r][c] = xs[(size_t)(r0 + r) * NV + c];
    }
    __syncthreads();

    // a1 = elu(x @ wfc1_w + b)  — v-outer, 8 independent chains
    float acc1[8];
    #pragma unroll
    for (int j = 0; j < 8; ++j) acc1[j] = wfc1_b[tc + 16 * j];
    for (int v = 0; v < NV; ++v) {
        const float xv = sx[tr][v];
        #pragma unroll
        for (int j = 0; j < 8; ++j)
            acc1[j] = fmaf(xv, wfc1_w[v * NH + tc + 16 * j], acc1[j]);
    }
    #pragma unroll
    for (int j = 0; j < 8; ++j) sa[tr][tc + 16 * j] = elu_f(acc1[j]);
    __syncthreads();

    // a2 = a1 @ wfc2_w + b
    float acc2[8];
    #pragma unroll
    for (int j = 0; j < 8; ++j) acc2[j] = wfc2_b[tc + 16 * j];
    for (int h = 0; h < NH; ++h) {
        const float av = sa[tr][h];
        #pragma unroll
        for (int j = 0; j < 8; ++j)
            acc2[j] = fmaf(av, wfc2_w[h * NH + tc + 16 * j], acc2[j]);
    }
    __syncthreads();
    #pragma unroll
    for (int j = 0; j < 8; ++j) sa[tr][tc + 16 * j] = acc2[j];
    __syncthreads();

    // g = a2 @ wglu_w + b  (408 cols) — h-outer, 26 chains
    float accg[26];
    #pragma unroll
    for (int gi = 0; gi < 26; ++gi) {
        const int c = tc + 16 * gi;
        accg[gi] = (c < 2 * NV) ? wglu_b[c] : 0.f;
    }
    for (int h = 0; h < NH; ++h) {
        const float av = sa[tr][h];
        #pragma unroll
        for (int gi = 0; gi < 26; ++gi) {
            const int c = tc + 16 * gi;
            if (c < 2 * NV) accg[gi] = fmaf(av, wglu_w[h * (2 * NV) + c], accg[gi]);
        }
    }
    __syncthreads();
    #pragma unroll
    for (int gi = 0; gi < 26; ++gi) {
        const int c = tc + 16 * gi;
        if (c < 2 * NV) sg[tr][c] = accg[gi];
    }
    __syncthreads();

    // hg = g[:V]*sigmoid(g[V:]); t = x + hg; LN over 204; softmax
    float tv[13];
    float s1 = 0.f, s2 = 0.f;
    #pragma unroll
    for (int ii = 0; ii < 13; ++ii) {
        const int c = tc + 16 * ii;
        float val = 0.f;
        if (c < NV) {
            const float hg = sg[tr][c] * sigm_f(sg[tr][c + NV]);
            val = sx[tr][c] + hg;
            s1 += val; s2 = fmaf(val, val, s2);
        }
        tv[ii] = val;
    }
    #pragma unroll
    for (int m = 1; m <= 8; m <<= 1) { s1 += __shfl_xor(s1, m); s2 += __shfl_xor(s2, m); }
    const float mu  = s1 * (1.f / 204.f);
    const float var = s2 * (1.f / 204.f) - mu * mu;
    const float rs  = rsqrtf(fmaxf(var, 0.f) + 1e-5f);

    float mx = -1e30f;
    #pragma unroll
    for (int ii = 0; ii < 13; ++ii) {
        const int c = tc + 16 * ii;
        if (c < NV) {
            const float y = fmaf((tv[ii] - mu) * rs, wln_g[c], wln_b[c]);
            tv[ii] = y;
            mx = fmaxf(mx, y);
        }
    }
    #pragma unroll
    for (int m = 1; m <= 8; m <<= 1) mx = fmaxf(mx, __shfl_xor(mx, m));
    float se = 0.f;
    #pragma unroll
    for (int ii = 0; ii < 13; ++ii) {
        const int c = tc + 16 * ii;
        if (c < NV) {
            const float e = __expf(tv[ii] - mx);
            tv[ii] = e;
            se += e;
        }
    }
    #pragma unroll
    for (int m = 1; m <= 8; m <<= 1) se += __shfl_xor(se, m);
    const float inv = 1.f / se;
    #pragma unroll
    for (int ii = 0; ii < 13; ++ii) {
        const int c = tc + 16 * ii;
        if (c < NV) wts[(size_t)(r0 + tr) * NV + c] = tv[ii] * inv;
    }
}

// ---------------- main fused kernel ----------------
// grid = 64 M-blocks x 8 v-groups; block = 256 (4 waves, each 16 rows => M=64).
// Per v: stage glu[v] -> LDS (all waves); GEMM1 B from global (shared v => L2);
// h2 -> per-wave LDS; barrier; GEMM2 B from LDS (XOR-swizzled, conflict-free);
// GLU+skip+LN in regs; acc_out += wts*var_out; epilogue atomicAdd.
__global__ __launch_bounds__(256, 2) void k_main(
    const float*  __restrict__ xs,
    const float*  __restrict__ fc1_w,
    const float*  __restrict__ fc1_b,
    const float*  __restrict__ fc2_b,
    const float*  __restrict__ glu_b,
    const float*  __restrict__ skip_w,
    const float*  __restrict__ skip_b,
    const float*  __restrict__ ln_g,
    const float*  __restrict__ ln_b,
    const __bf16* __restrict__ fc2t,   // [v][n][k] bf16
    const __bf16* __restrict__ glu16,  // [v][g][k] bf16, row-chunks pre-swizzled
    const float*  __restrict__ wts,
    float*        __restrict__ out)
{
    __shared__ __bf16 s_glu[NG * NH];      // 64 KB, one v (swizzled rows)
    __shared__ __bf16 s_h2[4][16 * NH];    // 16 KB, per-wave h2

    const int tid = threadIdx.x;
    const int w   = tid >> 6;
    const int l   = tid & 63;
    const int l15 = l & 15;
    const int lg  = l >> 4;

    const int vg = blockIdx.x & 7;                    // v-group == XCD
    const int m0 = (blockIdx.x >> 3) * 64 + w * 16;   // this wave's 16 rows
    const int nv = (NV - vg + 7) >> 3;

    float lngv[8], lnbv[8];
    #pragma unroll
    for (int j = 0; j < 8; ++j) {
        lngv[j] = ln_g[j * 16 + l15];
        lnbv[j] = ln_b[j * 16 + l15];
    }

    const f32x4 zero4 = {0.f, 0.f, 0.f, 0.f};
    f32x4 acc_out[8];
    #pragma unroll
    for (int j = 0; j < 8; ++j) acc_out[j] = zero4;

    __bf16* h2b = &s_h2[w][0];

    for (int i = 0; i < nv; ++i) {
        const int v = vg + 8 * i;

        // ---- stage glu[v] (64 KB) into LDS: wave w moves bytes [w*16K, w*16K+16K)
        {
            const char* sbase = (const char*)(glu16 + (size_t)v * (NG * NH)) + w * 16384;
            char*       dbase = (char*)&s_glu[0] + w * 16384;
            #pragma unroll
            for (int s = 0; s < 16; ++s)
                stage16(sbase + s * 1024 + l * 16, dbase + s * 1024);
        }

        const float xv = xs[(size_t)(m0 + l15) * NV + v];
        const float wv = wts[(size_t)(m0 + l15) * NV + v];

        // ---- A1 fragments: row = l15, k = kb*32 + lg*8 + b
        bf16x8 a1[4];
        #pragma unroll
        for (int kb = 0; kb < 4; ++kb) {
            const int k0 = kb * 32 + lg * 8;
            const float4 w0 = *(const float4*)(fc1_w + v * NH + k0);
            const float4 w1 = *(const float4*)(fc1_w + v * NH + k0 + 4);
            const float4 b0 = *(const float4*)(fc1_b + v * NH + k0);
            const float4 b1 = *(const float4*)(fc1_b + v * NH + k0 + 4);
            bf16x8 af;
            af[0] = (__bf16)elu_f(fmaf(xv, w0.x, b0.x));
            af[1] = (__bf16)elu_f(fmaf(xv, w0.y, b0.y));
            af[2] = (__bf16)elu_f(fmaf(xv, w0.z, b0.z));
            af[3] = (__bf16)elu_f(fmaf(xv, w0.w, b0.w));
            af[4] = (__bf16)elu_f(fmaf(xv, w1.x, b1.x));
            af[5] = (__bf16)elu_f(fmaf(xv, w1.y, b1.y));
            af[6] = (__bf16)elu_f(fmaf(xv, w1.z, b1.z));
            af[7] = (__bf16)elu_f(fmaf(xv, w1.w, b1.w));
            a1[kb] = af;
        }

        // ---- GEMM1: h2 = h1 @ fc2_w[v] + fc2_b -> per-wave LDS (swizzled)
        #pragma unroll
        for (int j = 0; j < 8; ++j) {
            f32x4 acc = zero4;
            const __bf16* bp = fc2t + ((size_t)v * NH + j * 16 + l15) * NH + lg * 8;
            #pragma unroll
            for (int kb = 0; kb < 4; ++kb) {
                const bf16x8 bf = *(const bf16x8*)(bp + kb * 32);
                acc = __builtin_amdgcn_mfma_f32_16x16x32_bf16(a1[kb], bf, acc, 0, 0, 0);
            }
            const float bias = fc2_b[v * NH + j * 16 + l15];
            const int colb = (j * 16 + l15) * 2;
            #pragma unroll
            for (int r = 0; r < 4; ++r) {
                const int row = lg * 4 + r;   // D row = (lane>>4)*4 + reg  [m89]
                h2b[row * NH + ((colb ^ ((row & 7) << 4)) >> 1)] = (__bf16)(acc[r] + bias);
            }
        }

        asm volatile("s_waitcnt lgkmcnt(0)" ::: "memory");  // wave-local LDS flush

        // ---- A2 fragments: row = l15, k2 = kb*32 + lg*8 + b (same swizzle)
        bf16x8 a2[4];
        #pragma unroll
        for (int kb = 0; kb < 4; ++kb) {
            const int off = ((kb * 64 + lg * 16) ^ ((l15 & 7) << 4)) >> 1;
            a2[kb] = *(const bf16x8*)(h2b + l15 * NH + off);
        }

        __syncthreads();   // drains stage vmcnt; s_glu[v] ready for all waves

        // ---- GEMM2 phase A: fc_out cols (j2 = 0..7), B from swizzled LDS
        f32x4 fco[8];
        const int r7 = l15 & 7;
        #pragma unroll
        for (int j2 = 0; j2 < 8; ++j2) {
            f32x4 acc = zero4;
            const int row = j2 * 16 + l15;
            #pragma unroll
            for (int kb = 0; kb < 4; ++kb) {
                const int cb = ((kb * 4 + lg) ^ r7) * 16;
                const bf16x8 bf = *(const bf16x8*)((const char*)s_glu + row * 256 + cb);
                acc = __builtin_amdgcn_mfma_f32_16x16x32_bf16(a2[kb], bf, acc, 0, 0, 0);
            }
            const float gb = glu_b[v * NG + j2 * 16 + l15];
            acc[0] += gb; acc[1] += gb; acc[2] += gb; acc[3] += gb;
            fco[j2] = acc;
        }

        // x / wts broadcast to D rows (rows 0..15 live in lanes 0..15)
        float xrow[4], wrow[4];
        #pragma unroll
        for (int r = 0; r < 4; ++r) {
            xrow[r] = __shfl(xv, lg * 4 + r);
            wrow[r] = __shfl(wv, lg * 4 + r);
        }

        // ---- GEMM2 phase B: gate cols (j2 = 8..15) + GLU + skip
        float sv[8][4];
        #pragma unroll
        for (int j = 0; j < 8; ++j) {
            f32x4 acc = zero4;
            const int row = (j + 8) * 16 + l15;
            #pragma unroll
            for (int kb = 0; kb < 4; ++kb) {
                const int cb = ((kb * 4 + lg) ^ r7) * 16;
                const bf16x8 bf = *(const bf16x8*)((const char*)s_glu + row * 256 + cb);
                acc = __builtin_amdgcn_mfma_f32_16x16x32_bf16(a2[kb], bf, acc, 0, 0, 0);
            }
            const float gb = glu_b[v * NG + NH + j * 16 + l15];
            const float sw = skip_w[v * NH + j * 16 + l15];
            const float sb = skip_b[v * NH + j * 16 + l15];
            #pragma unroll
            for (int r = 0; r < 4; ++r) {
                const float h3 = fco[j][r] * sigm_f(acc[r] + gb);
                sv[j][r] = fmaf(xrow[r], sw, sb) + h3;
            }
        }

        // ---- LN over H per row + weighted accumulate
        #pragma unroll
        for (int r = 0; r < 4; ++r) {
            float s1 = 0.f, s2 = 0.f;
            #pragma unroll
            for (int j = 0; j < 8; ++j) { s1 += sv[j][r]; s2 = fmaf(sv[j][r], sv[j][r], s2); }
            #pragma unroll
            for (int m = 1; m <= 8; m <<= 1) { s1 += __shfl_xor(s1, m); s2 += __shfl_xor(s2, m); }
            const float mu  = s1 * (1.f / 128.f);
            const float var = s2 * (1.f / 128.f) - mu * mu;
            const float rsv = rsqrtf(fmaxf(var, 0.f) + 1e-5f);
            const float wt  = wrow[r];
            #pragma unroll
            for (int j = 0; j < 8; ++j) {
                const float y = fmaf((sv[j][r] - mu) * rsv, lngv[j], lnbv[j]);
                acc_out[j][r] = fmaf(wt, y, acc_out[j][r]);
            }
        }

        __syncthreads();   // all waves done reading s_glu before next stage
    }

    // ---- epilogue: this wave owns its 16 rows; 8 v-groups contend per element
    #pragma unroll
    for (int j = 0; j < 8; ++j) {
        #pragma unroll
        for (int r = 0; r < 4; ++r)
            atomicAdd(&out[(size_t)(m0 + lg * 4 + r) * NH + j * 16 + l15], acc_out[j][r]);
    }
}

extern "C" void kernel_launch(void* const* d_in, const int* in_sizes, int n_in,
                              void* d_out, int out_size, void* d_ws, size_t ws_size,
                              hipStream_t stream) {
    (void)in_sizes; (void)n_in; (void)out_size; (void)ws_size;

    const float* xs     = (const float*)d_in[0];
    const float* fc1_w  = (const float*)d_in[1];
    const float* fc1_b  = (const float*)d_in[2];
    const float* fc2_w  = (const float*)d_in[3];
    const float* fc2_b  = (const float*)d_in[4];
    const float* glu_w  = (const float*)d_in[5];
    const float* glu_b  = (const float*)d_in[6];
    const float* skip_w = (const float*)d_in[7];
    const float* skip_b = (const float*)d_in[8];
    const float* ln_g   = (const float*)d_in[9];
    const float* ln_b   = (const float*)d_in[10];
    const float* wfc1_w = (const float*)d_in[11];
    const float* wfc1_b = (const float*)d_in[12];
    const float* wfc2_w = (const float*)d_in[13];
    const float* wfc2_b = (const float*)d_in[14];
    const float* wglu_w = (const float*)d_in[15];
    const float* wglu_b = (const float*)d_in[16];
    const float* wln_g  = (const float*)d_in[17];
    const float* wln_b  = (const float*)d_in[18];

    float* out = (float*)d_out;
    float* wts = out + (size_t)NROWS * NH;

    __bf16* fc2t  = (__bf16*)d_ws;
    __bf16* glu16 = fc2t + (size_t)NV * NH * NH;

    hipMemsetAsync(d_out, 0, (size_t)NROWS * NH * sizeof(float), stream);

    k_prep_fc2<<<NV, 256, 0, stream>>>(fc2_w, fc2t);

    const int nchunks = NV * NG * (NH / 8);
    k_cvt_glu<<<(nchunks + 255) / 256, 256, 0, stream>>>(glu_w, glu16);

    k_wts<<<NROWS / 16, 256, 0, stream>>>(xs, wfc1_w, wfc1_b, wfc2_w, wfc2_b,
                                          wglu_w, wglu_b, wln_g, wln_b, wts);

    k_main<<<(NROWS / 64) * 8, 256, 0, stream>>>(xs, fc1_w, fc1_b, fc2_b, glu_b,
                                                 skip_w, skip_b, ln_g, ln_b,
                                                 fc2t, glu16, wts, out);
}

// Round 3
// 515.286 us; speedup vs baseline: 2.2393x; 1.1008x over previous
//
#include <hip/hip_runtime.h>
#include <hip/hip_bf16.h>

#define NROWS 4096
#define NV    204
#define NH    128
#define NG    256

typedef __bf16 bf16x8 __attribute__((ext_vector_type(8)));
typedef float  f32x4  __attribute__((ext_vector_type(4)));

__device__ __forceinline__ float elu_f(float x)  { return x > 0.f ? x : __expf(x) - 1.f; }
__device__ __forceinline__ float sigm_f(float x) { return 1.f / (1.f + __expf(-x)); }

__device__ __forceinline__ void stage16(const void* g, void* l) {
    __builtin_amdgcn_global_load_lds((const __attribute__((address_space(1))) void*)g,
                                     (__attribute__((address_space(3))) void*)l, 16, 0, 0);
}

// wave w copies 8KB of a 32KB half-tile: LDS linear, global per-lane (m104/m173)
__device__ __forceinline__ void stage_half(const __bf16* src, __bf16* dst, int w, int l) {
    const char* sb = (const char*)src + w * 8192;
    char*       db = (char*)dst + w * 8192;
    #pragma unroll
    for (int s = 0; s < 8; ++s)
        stage16(sb + s * 1024 + l * 16, db + s * 1024);
}

// ============ fused setup: fc2 transpose+cvt | glu cvt+preswizzle | wts path ============
#define NB_FC2 NV
#define NB_GLU (NV * 16)          // NV*NG*(NH/8)/256 = 3264
#define NB_WTS (NROWS / 8)        // 512

__global__ __launch_bounds__(256) void k_setup(
    const float* __restrict__ fc2_w, __bf16* __restrict__ fc2t,
    const float* __restrict__ glu_w, __bf16* __restrict__ glu16,
    const float* __restrict__ xs,
    const float* __restrict__ wfc1_w, const float* __restrict__ wfc1_b,
    const float* __restrict__ wfc2_w, const float* __restrict__ wfc2_b,
    const float* __restrict__ wglu_w, const float* __restrict__ wglu_b,
    const float* __restrict__ wln_g,  const float* __restrict__ wln_b,
    float* __restrict__ wts)
{
    __shared__ float tile[64 * 129];          // fc2 branch
    __shared__ float sx[8][NV];               // wts branch
    __shared__ float sa[8][NH];
    __shared__ float sg[8][2 * NV];

    const int b = blockIdx.x;
    const int t = threadIdx.x;

    if (b < NB_FC2) {
        // ---- fc2t[v][n][k] = (bf16) fc2_w[v][k][n] ----
        const int v = b;
        const float* s = fc2_w + (size_t)v * (NH * NH);
        __bf16*      d = fc2t + (size_t)v * (NH * NH);
        for (int h = 0; h < 2; ++h) {
            __syncthreads();
            for (int i = t; i < 64 * 32; i += 256) {
                const int k = i >> 5, n4 = (i & 31) * 4;
                const float4 f = *(const float4*)(s + (h * 64 + k) * 128 + n4);
                tile[k * 129 + n4 + 0] = f.x;
                tile[k * 129 + n4 + 1] = f.y;
                tile[k * 129 + n4 + 2] = f.z;
                tile[k * 129 + n4 + 3] = f.w;
            }
            __syncthreads();
            for (int i = t; i < 128 * 8; i += 256) {
                const int n = i >> 3, kc = (i & 7) * 8;
                bf16x8 o;
                #pragma unroll
                for (int q = 0; q < 8; ++q) o[q] = (__bf16)tile[(kc + q) * 129 + n];
                *(bf16x8*)(d + n * 128 + h * 64 + kc) = o;
            }
        }
        return;
    }

    if (b < NB_FC2 + NB_GLU) {
        // ---- glu16 cvt, 16B chunk ch of row g stored at ch^(g&7) ----
        const int idx = (b - NB_FC2) * 256 + t;
        const int ch = idx & 15;
        const int g  = (idx >> 4) & 255;
        const int v  = idx >> 12;
        const float* sp = glu_w + (((size_t)v * NG + g) * NH + ch * 8);
        bf16x8 o;
        #pragma unroll
        for (int q = 0; q < 8; ++q) o[q] = (__bf16)sp[q];
        const int dch = ch ^ (g & 7);
        *(bf16x8*)(glu16 + (((size_t)v * NG + g) * NH) + dch * 8) = o;
        return;
    }

    // ---- wts = softmax(LN(x + GLU(MLP(x)))), 8 rows/block, 32 lanes/row ----
    const int r0 = (b - NB_FC2 - NB_GLU) * 8;
    const int tr = t >> 5;
    const int tc = t & 31;

    for (int i = t; i < 8 * NV; i += 256) {
        const int r = i / NV, c = i - r * NV;
        sx[r][c] = xs[(size_t)(r0 + r) * NV + c];
    }
    __syncthreads();

    // a1 = elu(x @ wfc1_w + b) — 4 chains
    float acc1[4];
    #pragma unroll
    for (int j = 0; j < 4; ++j) acc1[j] = wfc1_b[tc + 32 * j];
    for (int v = 0; v < NV; ++v) {
        const float xv = sx[tr][v];
        #pragma unroll
        for (int j = 0; j < 4; ++j)
            acc1[j] = fmaf(xv, wfc1_w[v * NH + tc + 32 * j], acc1[j]);
    }
    #pragma unroll
    for (int j = 0; j < 4; ++j) sa[tr][tc + 32 * j] = elu_f(acc1[j]);
    __syncthreads();

    // a2 = a1 @ wfc2_w + b
    float acc2[4];
    #pragma unroll
    for (int j = 0; j < 4; ++j) acc2[j] = wfc2_b[tc + 32 * j];
    for (int h = 0; h < NH; ++h) {
        const float av = sa[tr][h];
        #pragma unroll
        for (int j = 0; j < 4; ++j)
            acc2[j] = fmaf(av, wfc2_w[h * NH + tc + 32 * j], acc2[j]);
    }
    __syncthreads();
    #pragma unroll
    for (int j = 0; j < 4; ++j) sa[tr][tc + 32 * j] = acc2[j];
    __syncthreads();

    // g = a2 @ wglu_w + b (408 cols): 12 full chains + guarded tail
    float accg[13];
    #pragma unroll
    for (int gi = 0; gi < 12; ++gi) accg[gi] = wglu_b[tc + 32 * gi];
    accg[12] = (tc < 24) ? wglu_b[tc + 384] : 0.f;
    for (int h = 0; h < NH; ++h) {
        const float av = sa[tr][h];
        #pragma unroll
        for (int gi = 0; gi < 12; ++gi)
            accg[gi] = fmaf(av, wglu_w[h * (2 * NV) + tc + 32 * gi], accg[gi]);
        if (tc < 24) accg[12] = fmaf(av, wglu_w[h * (2 * NV) + tc + 384], accg[12]);
    }
    __syncthreads();
    #pragma unroll
    for (int gi = 0; gi < 12; ++gi) sg[tr][tc + 32 * gi] = accg[gi];
    if (tc < 24) sg[tr][tc + 384] = accg[12];
    __syncthreads();

    // hg = g[:V]*sigmoid(g[V:]); t = x + hg; LN over 204; softmax
    float tv[7];
    float s1 = 0.f, s2 = 0.f;
    #pragma unroll
    for (int ii = 0; ii < 7; ++ii) {
        const int c = tc + 32 * ii;
        float val = 0.f;
        if (c < NV) {
            const float hg = sg[tr][c] * sigm_f(sg[tr][c + NV]);
            val = sx[tr][c] + hg;
            s1 += val; s2 = fmaf(val, val, s2);
        }
        tv[ii] = val;
    }
    #pragma unroll
    for (int m = 1; m <= 16; m <<= 1) { s1 += __shfl_xor(s1, m); s2 += __shfl_xor(s2, m); }
    const float mu  = s1 * (1.f / 204.f);
    const float var = s2 * (1.f / 204.f) - mu * mu;
    const float rs  = rsqrtf(fmaxf(var, 0.f) + 1e-5f);

    float mx = -1e30f;
    #pragma unroll
    for (int ii = 0; ii < 7; ++ii) {
        const int c = tc + 32 * ii;
        if (c < NV) {
            const float y = fmaf((tv[ii] - mu) * rs, wln_g[c], wln_b[c]);
            tv[ii] = y;
            mx = fmaxf(mx, y);
        }
    }
    #pragma unroll
    for (int m = 1; m <= 16; m <<= 1) mx = fmaxf(mx, __shfl_xor(mx, m));
    float se = 0.f;
    #pragma unroll
    for (int ii = 0; ii < 7; ++ii) {
        const int c = tc + 32 * ii;
        if (c < NV) {
            const float e = __expf(tv[ii] - mx);
            tv[ii] = e;
            se += e;
        }
    }
    #pragma unroll
    for (int m = 1; m <= 16; m <<= 1) se += __shfl_xor(se, m);
    const float inv = 1.f / se;
    #pragma unroll
    for (int ii = 0; ii < 7; ++ii) {
        const int c = tc + 32 * ii;
        if (c < NV) wts[(size_t)(r0 + tr) * NV + c] = tv[ii] * inv;
    }
}

// ============ main fused kernel, software-pipelined half-tile staging ============
// grid = 64 M-blocks x 8 v-groups; block = 256 (4 waves x 16 rows = M64).
// Phase alpha(v): [stage gate[v]] A1, GEMM1->h2, A2, GEMM2-A from s_fc. barrier.
// Phase beta(v):  [stage fc[v+1]] GEMM2-B from s_gate, GLU, skip, LN, acc. barrier.
// Each 32KB stage overlaps one full compute phase before its drain.
__global__ __launch_bounds__(256, 2) void k_main(
    const float*  __restrict__ xs,
    const float*  __restrict__ fc1_w,
    const float*  __restrict__ fc1_b,
    const float*  __restrict__ fc2_b,
    const float*  __restrict__ glu_b,
    const float*  __restrict__ skip_w,
    const float*  __restrict__ skip_b,
    const float*  __restrict__ ln_g,
    const float*  __restrict__ ln_b,
    const __bf16* __restrict__ fc2t,   // [v][n][k] bf16
    const __bf16* __restrict__ glu16,  // [v][g][k] bf16, chunks pre-swizzled
    const float*  __restrict__ wts,
    float*        __restrict__ out)
{
    __shared__ __bf16 s_fc[128 * NH];     // 32 KB: glu rows 0..127 (fc_out cols)
    __shared__ __bf16 s_gate[128 * NH];   // 32 KB: glu rows 128..255 (gate cols)
    __shared__ __bf16 s_h2[4][16 * NH];   // 16 KB: per-wave h2

    const int tid = threadIdx.x;
    const int w   = tid >> 6;
    const int l   = tid & 63;
    const int l15 = l & 15;
    const int lg  = l >> 4;
    const int r7  = l15 & 7;

    const int vg = blockIdx.x & 7;                    // v-group == XCD
    const int m0 = (blockIdx.x >> 3) * 64 + w * 16;   // this wave's 16 rows
    const int nv = (NV - vg + 7) >> 3;

    float lngv[8], lnbv[8];
    #pragma unroll
    for (int j = 0; j < 8; ++j) {
        lngv[j] = ln_g[j * 16 + l15];
        lnbv[j] = ln_b[j * 16 + l15];
    }

    const f32x4 zero4 = {0.f, 0.f, 0.f, 0.f};
    f32x4 acc_out[8];
    #pragma unroll
    for (int j = 0; j < 8; ++j) acc_out[j] = zero4;

    __bf16* h2b = &s_h2[w][0];

    // ---- prologue: stage fc half of v0, prefetch scalars ----
    stage_half(glu16 + (size_t)vg * (NG * NH), s_fc, w, l);
    float xv = xs[(size_t)(m0 + l15) * NV + vg];
    float wv = wts[(size_t)(m0 + l15) * NV + vg];
    __syncthreads();

    for (int i = 0; i < nv; ++i) {
        const int v = vg + 8 * i;

        // ================= phase alpha =================
        stage_half(glu16 + (size_t)v * (NG * NH) + 128 * NH, s_gate, w, l);

        // ---- A1 fragments: row = l15, k = kb*32 + lg*8 + b
        bf16x8 a1[4];
        #pragma unroll
        for (int kb = 0; kb < 4; ++kb) {
            const int k0 = kb * 32 + lg * 8;
            const float4 w0 = *(const float4*)(fc1_w + v * NH + k0);
            const float4 w1 = *(const float4*)(fc1_w + v * NH + k0 + 4);
            const float4 b0 = *(const float4*)(fc1_b + v * NH + k0);
            const float4 b1 = *(const float4*)(fc1_b + v * NH + k0 + 4);
            bf16x8 af;
            af[0] = (__bf16)elu_f(fmaf(xv, w0.x, b0.x));
            af[1] = (__bf16)elu_f(fmaf(xv, w0.y, b0.y));
            af[2] = (__bf16)elu_f(fmaf(xv, w0.z, b0.z));
            af[3] = (__bf16)elu_f(fmaf(xv, w0.w, b0.w));
            af[4] = (__bf16)elu_f(fmaf(xv, w1.x, b1.x));
            af[5] = (__bf16)elu_f(fmaf(xv, w1.y, b1.y));
            af[6] = (__bf16)elu_f(fmaf(xv, w1.z, b1.z));
            af[7] = (__bf16)elu_f(fmaf(xv, w1.w, b1.w));
            a1[kb] = af;
        }

        // ---- GEMM1: h2 = h1 @ fc2_w[v] + fc2_b -> per-wave LDS (swizzled)
        #pragma unroll
        for (int j = 0; j < 8; ++j) {
            f32x4 acc = zero4;
            const __bf16* bp = fc2t + ((size_t)v * NH + j * 16 + l15) * NH + lg * 8;
            #pragma unroll
            for (int kb = 0; kb < 4; ++kb) {
                const bf16x8 bf = *(const bf16x8*)(bp + kb * 32);
                acc = __builtin_amdgcn_mfma_f32_16x16x32_bf16(a1[kb], bf, acc, 0, 0, 0);
            }
            const float bias = fc2_b[v * NH + j * 16 + l15];
            const int colb = (j * 16 + l15) * 2;
            #pragma unroll
            for (int r = 0; r < 4; ++r) {
                const int row = lg * 4 + r;   // D row = (lane>>4)*4 + reg  [m89]
                h2b[row * NH + ((colb ^ ((row & 7) << 4)) >> 1)] = (__bf16)(acc[r] + bias);
            }
        }

        asm volatile("s_waitcnt lgkmcnt(0)" ::: "memory");  // wave-local LDS flush

        // ---- A2 fragments: row = l15, k2 = kb*32 + lg*8 + b (same swizzle)
        bf16x8 a2[4];
        #pragma unroll
        for (int kb = 0; kb < 4; ++kb) {
            const int off = ((kb * 64 + lg * 16) ^ (r7 << 4)) >> 1;
            a2[kb] = *(const bf16x8*)(h2b + l15 * NH + off);
        }

        // ---- GEMM2 phase A: fc_out cols from s_fc (staged during prev beta)
        f32x4 fco[8];
        #pragma unroll
        for (int j2 = 0; j2 < 8; ++j2) {
            f32x4 acc = zero4;
            const int row = j2 * 16 + l15;
            #pragma unroll
            for (int kb = 0; kb < 4; ++kb) {
                const int cb = ((kb * 4 + lg) ^ r7) * 16;
                const bf16x8 bf = *(const bf16x8*)((const char*)s_fc + row * 256 + cb);
                acc = __builtin_amdgcn_mfma_f32_16x16x32_bf16(a2[kb], bf, acc, 0, 0, 0);
            }
            const float gb = glu_b[v * NG + j2 * 16 + l15];
            acc[0] += gb; acc[1] += gb; acc[2] += gb; acc[3] += gb;
            fco[j2] = acc;
        }

        __syncthreads();   // s_gate[v] ready; all waves done with s_fc[v]

        // ================= phase beta =================
        if (i + 1 < nv)
            stage_half(glu16 + (size_t)(v + 8) * (NG * NH), s_fc, w, l);

        float xv_n = 0.f, wv_n = 0.f;
        if (i + 1 < nv) {
            xv_n = xs[(size_t)(m0 + l15) * NV + v + 8];
            wv_n = wts[(size_t)(m0 + l15) * NV + v + 8];
        }

        // x / wts broadcast to D rows (rows 0..15 live in lanes 0..15)
        float xrow[4], wrow[4];
        #pragma unroll
        for (int r = 0; r < 4; ++r) {
            xrow[r] = __shfl(xv, lg * 4 + r);
            wrow[r] = __shfl(wv, lg * 4 + r);
        }

        // ---- GEMM2 phase B: gate cols from s_gate + GLU + skip
        float sv[8][4];
        #pragma unroll
        for (int j = 0; j < 8; ++j) {
            f32x4 acc = zero4;
            const int row = j * 16 + l15;   // local row within gate half
            #pragma unroll
            for (int kb = 0; kb < 4; ++kb) {
                const int cb = ((kb * 4 + lg) ^ r7) * 16;
                const bf16x8 bf = *(const bf16x8*)((const char*)s_gate + row * 256 + cb);
                acc = __builtin_amdgcn_mfma_f32_16x16x32_bf16(a2[kb], bf, acc, 0, 0, 0);
            }
            const float gb = glu_b[v * NG + NH + j * 16 + l15];
            const float sw = skip_w[v * NH + j * 16 + l15];
            const float sb = skip_b[v * NH + j * 16 + l15];
            #pragma unroll
            for (int r = 0; r < 4; ++r) {
                const float h3 = fco[j][r] * sigm_f(acc[r] + gb);
                sv[j][r] = fmaf(xrow[r], sw, sb) + h3;
            }
        }

        // ---- LN over H per row + weighted accumulate
        #pragma unroll
        for (int r = 0; r < 4; ++r) {
            float s1 = 0.f, s2 = 0.f;
            #pragma unroll
            for (int j = 0; j < 8; ++j) { s1 += sv[j][r]; s2 = fmaf(sv[j][r], sv[j][r], s2); }
            #pragma unroll
            for (int m = 1; m <= 8; m <<= 1) { s1 += __shfl_xor(s1, m); s2 += __shfl_xor(s2, m); }
            const float mu  = s1 * (1.f / 128.f);
            const float var = s2 * (1.f / 128.f) - mu * mu;
            const float rsv = rsqrtf(fmaxf(var, 0.f) + 1e-5f);
            const float wt  = wrow[r];
            #pragma unroll
            for (int j = 0; j < 8; ++j) {
                const float y = fmaf((sv[j][r] - mu) * rsv, lngv[j], lnbv[j]);
                acc_out[j][r] = fmaf(wt, y, acc_out[j][r]);
            }
        }

        xv = xv_n; wv = wv_n;
        __syncthreads();   // s_fc[v+1] ready; all waves done with s_gate[v]
    }

    // ---- epilogue: 8 v-groups contend per output element
    #pragma unroll
    for (int j = 0; j < 8; ++j) {
        #pragma unroll
        for (int r = 0; r < 4; ++r)
            atomicAdd(&out[(size_t)(m0 + lg * 4 + r) * NH + j * 16 + l15], acc_out[j][r]);
    }
}

extern "C" void kernel_launch(void* const* d_in, const int* in_sizes, int n_in,
                              void* d_out, int out_size, void* d_ws, size_t ws_size,
                              hipStream_t stream) {
    (void)in_sizes; (void)n_in; (void)out_size; (void)ws_size;

    const float* xs     = (const float*)d_in[0];
    const float* fc1_w  = (const float*)d_in[1];
    const float* fc1_b  = (const float*)d_in[2];
    const float* fc2_w  = (const float*)d_in[3];
    const float* fc2_b  = (const float*)d_in[4];
    const float* glu_w  = (const float*)d_in[5];
    const float* glu_b  = (const float*)d_in[6];
    const float* skip_w = (const float*)d_in[7];
    const float* skip_b = (const float*)d_in[8];
    const float* ln_g   = (const float*)d_in[9];
    const float* ln_b   = (const float*)d_in[10];
    const float* wfc1_w = (const float*)d_in[11];
    const float* wfc1_b = (const float*)d_in[12];
    const float* wfc2_w = (const float*)d_in[13];
    const float* wfc2_b = (const float*)d_in[14];
    const float* wglu_w = (const float*)d_in[15];
    const float* wglu_b = (const float*)d_in[16];
    const float* wln_g  = (const float*)d_in[17];
    const float* wln_b  = (const float*)d_in[18];

    float* out = (float*)d_out;
    float* wts = out + (size_t)NROWS * NH;

    __bf16* fc2t  = (__bf16*)d_ws;
    __bf16* glu16 = fc2t + (size_t)NV * NH * NH;

    hipMemsetAsync(d_out, 0, (size_t)NROWS * NH * sizeof(float), stream);

    k_setup<<<NB_FC2 + NB_GLU + NB_WTS, 256, 0, stream>>>(
        fc2_w, fc2t, glu_w, glu16,
        xs, wfc1_w, wfc1_b, wfc2_w, wfc2_b, wglu_w, wglu_b, wln_g, wln_b, wts);

    k_main<<<(NROWS / 64) * 8, 256, 0, stream>>>(xs, fc1_w, fc1_b, fc2_b, glu_b,
                                                 skip_w, skip_b, ln_g, ln_b,
                                                 fc2t, glu16, wts, out);
}